// Round 9
// baseline (118.298 us; speedup 1.0000x reference)
//
#include <hip/hip_runtime.h>
#include <stdint.h>

#define EPSF 1e-8f

using i32x4 = __attribute__((ext_vector_type(4))) int;

__device__ __forceinline__ float wave_sum(float v) {
#pragma unroll
  for (int off = 32; off > 0; off >>= 1) v += __shfl_down(v, off, 64);
  return v;
}
__device__ __forceinline__ float wave_max(float v) {
#pragma unroll
  for (int off = 32; off > 0; off >>= 1) v = fmaxf(v, __shfl_down(v, off, 64));
  return v;
}

// ---------------- fused prep: wquant (blocks 0..Dout-1) + xnorm (rest) ----
// wquant: ternary {-1,0,1} i8 (mask |w|>0.5*mean|w| invariant to row
// RMSNorm); scale[o] = mean|w| * rsqrt(mean(w^2)+EPS) * row_scale[o].
// xnorm: RMSNorm(x)*g, per-row symmetric i8 quant, sx[row] = amax/127.
__global__ __launch_bounds__(256) void prep_kernel(
    const float* __restrict__ x, const float* __restrict__ g,
    const float* __restrict__ w, const float* __restrict__ row_scale,
    signed char* __restrict__ xq, float* __restrict__ sx,
    signed char* __restrict__ wq, float* __restrict__ scale,
    int K, int Dout) {
  __shared__ float smA[4], smQ[4], smM[4];
  const int t = threadIdx.x;
  const int wid = t >> 6;
  if ((int)blockIdx.x < Dout) {
    const int row = blockIdx.x;
    const float* wr = w + (size_t)row * K;
    float4 v0 = reinterpret_cast<const float4*>(wr)[2 * t];
    float4 v1 = reinterpret_cast<const float4*>(wr)[2 * t + 1];
    float f[8] = {v0.x, v0.y, v0.z, v0.w, v1.x, v1.y, v1.z, v1.w};
    float sa = 0.f, sq = 0.f;
#pragma unroll
    for (int i = 0; i < 8; ++i) { sa += fabsf(f[i]); sq += f[i] * f[i]; }
    sa = wave_sum(sa);
    sq = wave_sum(sq);
    if ((t & 63) == 0) { smA[wid] = sa; smQ[wid] = sq; }
    __syncthreads();
    const float sumabs = smA[0] + smA[1] + smA[2] + smA[3];
    const float sumsq  = smQ[0] + smQ[1] + smQ[2] + smQ[3];
    const float absmean = sumabs / (float)K;
    const float thr = 0.5f * absmean;
    union { signed char c[8]; uint2 u; } pk;
#pragma unroll
    for (int i = 0; i < 8; ++i)
      pk.c[i] = (fabsf(f[i]) > thr)
                    ? (f[i] > 0.f ? (signed char)1 : (signed char)-1)
                    : (signed char)0;
    reinterpret_cast<uint2*>(wq + (size_t)row * K)[t] = pk.u;
    if (t == 0)
      scale[row] = absmean * rsqrtf(sumsq / (float)K + EPSF) * row_scale[row];
  } else {
    const int row = blockIdx.x - Dout;
    const float* xr = x + (size_t)row * K;
    float4 v0 = reinterpret_cast<const float4*>(xr)[2 * t];
    float4 v1 = reinterpret_cast<const float4*>(xr)[2 * t + 1];
    float f[8] = {v0.x, v0.y, v0.z, v0.w, v1.x, v1.y, v1.z, v1.w};
    float sq = 0.f;
#pragma unroll
    for (int i = 0; i < 8; ++i) sq += f[i] * f[i];
    sq = wave_sum(sq);
    if ((t & 63) == 0) smQ[wid] = sq;
    __syncthreads();
    const float sumsq = smQ[0] + smQ[1] + smQ[2] + smQ[3];
    const float rs = rsqrtf(sumsq / (float)K + EPSF);
    float4 g0 = reinterpret_cast<const float4*>(g)[2 * t];
    float4 g1 = reinterpret_cast<const float4*>(g)[2 * t + 1];
    float gg[8] = {g0.x, g0.y, g0.z, g0.w, g1.x, g1.y, g1.z, g1.w};
    float vv[8]; float am = 0.f;
#pragma unroll
    for (int i = 0; i < 8; ++i) {
      vv[i] = f[i] * rs * gg[i];
      am = fmaxf(am, fabsf(vv[i]));
    }
    am = wave_max(am);
    if ((t & 63) == 0) smM[wid] = am;
    __syncthreads();
    const float amax = fmaxf(fmaxf(smM[0], smM[1]), fmaxf(smM[2], smM[3]));
    const float inv = amax > 0.f ? 127.f / amax : 0.f;
    union { signed char c[8]; uint2 u; } pk;
#pragma unroll
    for (int i = 0; i < 8; ++i)
      pk.c[i] = (signed char)__float2int_rn(vv[i] * inv);
    reinterpret_cast<uint2*>(xq + (size_t)row * K)[t] = pk.u;
    if (t == 0) sx[row] = amax > 0.f ? amax / 127.f : 0.f;
  }
}

// ---------------- i8 NT GEMM, 256x128 tile, 2 blocks/CU ----------------
// ROUND-9: TLP decorrelation. R8 analysis: MFMA-busy (28 us) == i8 peak
// floor; 63% idle = all 8 waves of the single resident block (LDS 128 KiB
// -> 1 block/CU) lockstepped on the same barrier/vmcnt. Fix: 256-thread
// blocks (4 waves, 2Mx2N), tile 256x128, BK=64, TRIPLE-buffered LDS
// (3 x 24 KiB = 72 KiB) -> 2 independent blocks/CU (144 KiB <= 160).
// Each SIMD hosts 1 wave from EACH block: when block A waits at VM/BAR,
// block B's wave feeds the MFMA pipe (m114 implicit overlap, restored).
// Per region (one BK=64 tile): stage tile t+2 into 3rd buffer (6 gload_lds),
// 12 ds_read_b128, 32 independent MFMA (each acc touched once -> max ILP).
// vmcnt ledger (prologue stages tiles 0,1 = 12 loads): entering region t
// outstanding = {stage(t) 6, stage(t+1) 6}; VM(6) drains stage(t) (its
// reads follow). Region t issues stage(t+2) -> back to 12. Tail: region
// NT-2 stages nothing (6 left), region NT-1 VM(0).
// Write hazard: stage(t+2) writes the buffer last read at region t-1,
// whose reads are consumed by region t-1 MFMAs before BAR(t) -> safe.
// Swizzle (64 B rows = 4 granules of 16 B): stored slot = g ^ ((row>>1)&3),
// inverse on global source (both-sides); read slot = kq ^ ((fr>>1)&3).
// Bank check: per 8-lane cycle group, period-slot p = ((fr&1)<<2)|slot
// spans all 8 values -> conflict-free (R8 measured 0 with the analogous map).

#define BAR() do { __builtin_amdgcn_sched_barrier(0); \
                   asm volatile("" ::: "memory"); \
                   __builtin_amdgcn_s_barrier(); \
                   asm volatile("" ::: "memory"); \
                   __builtin_amdgcn_sched_barrier(0); } while (0)
#define VM(n) asm volatile("s_waitcnt vmcnt(" #n ")" ::: "memory")

#define LDSBUF 24576  // A 256x64 (16384) + B 128x64 (8192)

__global__ __launch_bounds__(256, 2) void gemm_kernel(
    const signed char* __restrict__ A,   // [M][K] i8 (xq)
    const signed char* __restrict__ B,   // [N][K] i8 ternary (wq)
    const float* __restrict__ scale, const float* __restrict__ bias,
    const float* __restrict__ sx,
    float* __restrict__ C, int M, int N, int K) {
  __shared__ signed char lds[3 * LDSBUF];

  const int tid  = threadIdx.x;
  const int lane = tid & 63;
  const int wid  = tid >> 6;   // 0..3
  const int wm   = wid >> 1;   // 0..1 (row half)
  const int wn   = wid & 1;    // 0..1 (col half)
  const int fr   = lane & 15;
  const int kq   = lane >> 4;

  // chunked XCD swizzle (R2 mapping; grid 1024 % 8 == 0)
  const int nwg = gridDim.x;
  const int cpx = nwg >> 3;
  const int swz = (blockIdx.x & 7) * cpx + (blockIdx.x >> 3);
  const int NBN = N >> 7;                 // 128-wide col tiles
  const int bn = swz % NBN;
  const int bm = swz / NBN;
  const int mBase = bm * 256, nBase = bn * 128;

  const size_t Kb = (size_t)K;

  // staging: thread t -> rows sr(+64k), slot t&3; inverse-XOR source granule
  // (row deltas 64 keep (row>>1)&3 invariant: 32 ≡ 0 mod 4)
  const int sr = tid >> 2;                              // 0..63
  const int gsrc = (tid & 3) ^ ((sr >> 1) & 3);         // global granule
  const char* Abyte = (const char*)A + (size_t)(mBase + sr) * Kb + gsrc * 16;
  const char* Bbyte = (const char*)B + (size_t)(nBase + sr) * Kb + gsrc * 16;

#define STAGE(off, t) do { \
    _Pragma("unroll") for (int i_ = 0; i_ < 4; ++i_) \
      __builtin_amdgcn_global_load_lds( \
        (const __attribute__((address_space(1))) void*)(Abyte + (size_t)(64 * i_) * Kb + (size_t)(t) * 64), \
        (__attribute__((address_space(3))) void*)(&lds[(off) + i_ * 4096 + tid * 16]), 16, 0, 0); \
    _Pragma("unroll") for (int i_ = 0; i_ < 2; ++i_) \
      __builtin_amdgcn_global_load_lds( \
        (const __attribute__((address_space(1))) void*)(Bbyte + (size_t)(64 * i_) * Kb + (size_t)(t) * 64), \
        (__attribute__((address_space(3))) void*)(&lds[(off) + 16384 + i_ * 4096 + tid * 16]), 16, 0, 0); \
  } while (0)

  // reader constants: slot = kq ^ ((fr>>1)&3), rows ≡ fr mod 16 everywhere
  const int aSlot = ((kq ^ ((fr >> 1) & 3)) << 4);      // byte offset
  const int aRowB = (wm * 128 + fr) * 64;               // + mm*1024
  const int bRowB = 16384 + (wn * 64 + fr) * 64;        // + nn*1024

  i32x4 aF[8], bF[4];
  i32x4 acc[8][4];
#pragma unroll
  for (int m = 0; m < 8; ++m)
#pragma unroll
    for (int n = 0; n < 4; ++n) acc[m][n] = (i32x4){0, 0, 0, 0};

#define READS(off) do { \
    _Pragma("unroll") for (int mm = 0; mm < 8; ++mm) \
      aF[mm] = *(const i32x4*)&lds[(off) + aRowB + mm * 1024 + aSlot]; \
    _Pragma("unroll") for (int nn = 0; nn < 4; ++nn) \
      bF[nn] = *(const i32x4*)&lds[(off) + bRowB + nn * 1024 + aSlot]; \
  } while (0)

#define MFMAS() do { \
    __builtin_amdgcn_s_setprio(1); \
    _Pragma("unroll") for (int mm = 0; mm < 8; ++mm) \
    _Pragma("unroll") for (int nn = 0; nn < 4; ++nn) \
      acc[mm][nn] = __builtin_amdgcn_mfma_i32_16x16x64_i8( \
          aF[mm], bF[nn], acc[mm][nn], 0, 0, 0); \
    __builtin_amdgcn_s_setprio(0); } while (0)

  // ---- prologue: tiles 0,1 staged (12 loads) ----
  STAGE(0, 0);
  STAGE(LDSBUF, 1);
  unsigned int oRd = 0, oMid = LDSBUF, oWr = 2 * LDSBUF;

  const int NT = K >> 6;  // 2048/64 = 32 regions
  for (int t = 0; t < NT - 2; ++t) {
    VM(6); BAR();
    STAGE(oWr, t + 2);
    READS(oRd);
    MFMAS();
    const unsigned int tmp = oRd; oRd = oMid; oMid = oWr; oWr = tmp;
  }
  // region NT-2: nothing left to stage
  VM(6); BAR();
  READS(oRd);
  MFMAS();
  { const unsigned int tmp = oRd; oRd = oMid; oMid = oWr; oWr = tmp; }
  // region NT-1: drain all
  VM(0); BAR();
  READS(oRd);
  MFMAS();

  // ---- epilogue ----
  const int crowBase = mBase + wm * 128 + kq * 4;
  const int ccolBase = nBase + wn * 64 + fr;
  float sc[4], bi[4];
#pragma unroll
  for (int nn = 0; nn < 4; ++nn) {
    sc[nn] = scale[ccolBase + nn * 16];
    bi[nn] = bias[ccolBase + nn * 16];
  }
#pragma unroll
  for (int mm = 0; mm < 8; ++mm) {
    const int r0 = crowBase + mm * 16;
    float sxv[4];
#pragma unroll
    for (int r = 0; r < 4; ++r) sxv[r] = sx[r0 + r];
#pragma unroll
    for (int nn = 0; nn < 4; ++nn) {
      const int gc = ccolBase + nn * 16;
#pragma unroll
      for (int r = 0; r < 4; ++r)
        C[(size_t)(r0 + r) * (size_t)N + (size_t)gc] =
            (float)acc[mm][nn][r] * (sxv[r] * sc[nn]) + bi[nn];
    }
  }
#undef STAGE
#undef READS
#undef MFMAS
}

extern "C" void kernel_launch(void* const* d_in, const int* in_sizes, int n_in,
                              void* d_out, int out_size, void* d_ws, size_t ws_size,
                              hipStream_t stream) {
  const float* x         = (const float*)d_in[0];  // [B,S,Din]
  const float* weight    = (const float*)d_in[1];  // [Dout,Din]
  const float* row_scale = (const float*)d_in[2];  // [Dout,1]
  const float* bias      = (const float*)d_in[3];  // [Dout]
  const float* g         = (const float*)d_in[4];  // [Din]
  float* out = (float*)d_out;

  const int Din  = in_sizes[4];         // 2048
  const int Dout = in_sizes[3];         // 2048
  const int Mrows = in_sizes[0] / Din;  // 16384

  // ws: wq i8 [Dout*Din] | xq i8 [M*Din] | scale f32 [Dout] | sx f32 [M]
  char* ws = (char*)d_ws;
  signed char* wq = (signed char*)ws;
  signed char* xq = (signed char*)(ws + (size_t)Dout * Din);
  float* scale = (float*)(ws + (size_t)Dout * Din + (size_t)Mrows * Din);
  float* sx = scale + Dout;

  prep_kernel<<<Dout + Mrows, 256, 0, stream>>>(x, g, weight, row_scale,
                                                xq, sx, wq, scale, Din, Dout);
  const int grid = (Mrows / 256) * (Dout / 128);
  gemm_kernel<<<grid, 256, 0, stream>>>(xq, wq, scale, bias, sx, out,
                                        Mrows, Dout, Din);
}